// Round 2
// baseline (21442.195 us; speedup 1.0000x reference)
//
#include <hip/hip_runtime.h>
#include <hip/hip_bf16.h>
#include <math.h>

typedef __bf16 bf16;
typedef __bf16 bf16x8 __attribute__((ext_vector_type(8)));
typedef __bf16 bf16x4 __attribute__((ext_vector_type(4)));
typedef float f32x4 __attribute__((ext_vector_type(4)));

#define T_LEN 512
#define BATCH 64
#define HDIM  1024
#define IDIM  512

struct Ptr12 { const float* p[12]; };
struct Ptr6  { const float* p[6];  };

// ---------------------------------------------------------------------------
// K0: transpose + fp32->bf16 convert all weight matrices.
// z 0..5  : W_h (K=1024): hr_f, hz_f, hh_f, hr_b, hz_b, hh_b  -> wt_h [n][k]
// z 6..11 : W_x (K=512):  xr_f, xz_f, xh_f, xr_b, xz_b, xh_b  -> wt_x [n][k]
// ---------------------------------------------------------------------------
__global__ __launch_bounds__(256) void transpose_convert(Ptr12 W, bf16* wt_h, bf16* wt_x) {
    int z = blockIdx.z;
    int K = (z < 6) ? HDIM : IDIM;
    const float* src = W.p[z];
    bf16* dst = (z < 6) ? (wt_h + (size_t)z * HDIM * HDIM)
                        : (wt_x + (size_t)(z - 6) * HDIM * IDIM);
    int n0 = blockIdx.x * 32;
    int k0 = blockIdx.y * 32;
    if (k0 >= K) return;
    __shared__ float tile[32][33];
    int tx = threadIdx.x & 31, ty = threadIdx.x >> 5;  // ty 0..7
#pragma unroll
    for (int i = 0; i < 32; i += 8)
        tile[ty + i][tx] = src[(size_t)(k0 + ty + i) * HDIM + n0 + tx];
    __syncthreads();
#pragma unroll
    for (int i = 0; i < 32; i += 8)
        dst[(size_t)(n0 + ty + i) * K + k0 + tx] = (bf16)tile[tx][ty + i];
}

// ---------------------------------------------------------------------------
__global__ __launch_bounds__(256) void convert_x(const float* __restrict__ x, bf16* __restrict__ xbf) {
    size_t i = ((size_t)blockIdx.x * blockDim.x + threadIdx.x) * 4;
    float4 v = *(const float4*)(x + i);
    bf16x4 o = { (bf16)v.x, (bf16)v.y, (bf16)v.z, (bf16)v.w };
    *(bf16x4*)(xbf + i) = o;
}

// ---------------------------------------------------------------------------
__global__ __launch_bounds__(256) void init_h(const float* __restrict__ hf, const float* __restrict__ hb,
                                              bf16* __restrict__ h_cur) {
    int i = blockIdx.x * blockDim.x + threadIdx.x;  // 0..65535
    h_cur[i] = (bf16)hf[i];
    h_cur[BATCH * HDIM + i] = (bf16)hb[i];
}

// ---------------------------------------------------------------------------
// K1: xproj GEMM. XP[g][t][b][n] = (x @ W_x_g)[b*T+t][n] + bias_g[n], bf16.
// ---------------------------------------------------------------------------
__global__ __launch_bounds__(256) void xproj_gemm(const bf16* __restrict__ xbf,
                                                  const bf16* __restrict__ wt_x,
                                                  Ptr6 biases,
                                                  bf16* __restrict__ XP) {
    int g  = blockIdx.z;
    int m0 = blockIdx.x * 64;
    int n0 = blockIdx.y * 64;
    int w  = threadIdx.x >> 6;
    int l  = threadIdx.x & 63;
    int lm = l & 15, lq = l >> 4;

    const bf16* Wg    = wt_x + (size_t)g * HDIM * IDIM;
    const bf16* Abase = xbf + (size_t)(m0 + 16 * w + lm) * IDIM + lq * 8;
    const bf16* Bbase = Wg + (size_t)(n0 + lm) * IDIM + lq * 8;

    f32x4 acc[4] = {};
#pragma unroll 2
    for (int k = 0; k < IDIM; k += 32) {
        bf16x8 a = *(const bf16x8*)(Abase + k);
#pragma unroll
        for (int nt = 0; nt < 4; nt++) {
            bf16x8 b = *(const bf16x8*)(Bbase + (size_t)nt * 16 * IDIM + k);
            acc[nt] = __builtin_amdgcn_mfma_f32_16x16x32_bf16(a, b, acc[nt], 0, 0, 0);
        }
    }

    const float* bias = biases.p[g];
    int mrow = m0 + 16 * w + lq * 4;
#pragma unroll
    for (int nt = 0; nt < 4; nt++) {
        int n = n0 + nt * 16 + lm;
        float bv = bias[n];
#pragma unroll
        for (int r = 0; r < 4; r++) {
            int m = mrow + r;
            int b_ = m >> 9;       // batch
            int t  = m & 511;      // time
            XP[(((size_t)g * T_LEN + t) * BATCH + b_) * HDIM + n] = (bf16)(acc[nt][r] + bv);
        }
    }
}

// ---------------------------------------------------------------------------
// Device-scope per-direction barrier. Monotonic counter instance per use.
// ---------------------------------------------------------------------------
__device__ __forceinline__ void dir_barrier(unsigned* ctr, unsigned target) {
    __syncthreads();  // drains all waves' global stores (vmcnt(0) before s_barrier)
    if (threadIdx.x == 0) {
        __hip_atomic_fetch_add(ctr, 1u, __ATOMIC_RELEASE, __HIP_MEMORY_SCOPE_AGENT);
        while (__hip_atomic_load(ctr, __ATOMIC_ACQUIRE, __HIP_MEMORY_SCOPE_AGENT) < target)
            __builtin_amdgcn_s_sleep(2);
    }
    __syncthreads();
}

// ---------------------------------------------------------------------------
// K2: persistent recurrence kernel.
// 256 blocks (1/CU, 100KB LDS forces co-residency), 256 threads (4 waves).
// block = (dir, gb batch-half, s 16-col slice). Weights slice in LDS (once).
// Per step: phase A (R,Z GEMMs; publish Rh) -> dir-barrier ->
//           phase B (K-split h~ GEMM; LDS reduce; update h; write out) -> dir-barrier.
// ---------------------------------------------------------------------------
__global__ __launch_bounds__(256, 1) void gru_persist(const bf16* __restrict__ wt_h,
                                                      const bf16* __restrict__ XP,
                                                      bf16* __restrict__ h_all,
                                                      bf16* __restrict__ Rh_all,
                                                      float* __restrict__ out,
                                                      unsigned* __restrict__ bar) {
    // LDS: W fragments in exact MFMA B-operand order: slot(gate,kc,lane) of 8 bf16
    __shared__ bf16  Wlds[3 * 32 * 64 * 8];   // 98304 B
    __shared__ float Zlds[2][64][4];          // 2048 B
    __shared__ float Red[2][64][4];           // 2048 B

    int blk = blockIdx.x;
    int dir = blk >> 7;
    int gb  = (blk >> 6) & 1;
    int s   = blk & 63;
    int n0  = s * 16;

    int w = threadIdx.x >> 6, l = threadIdx.x & 63;
    int lm = l & 15, lq = l >> 4;

    bf16* h_d  = h_all  + (size_t)dir * BATCH * HDIM;
    bf16* Rh_d = Rh_all + (size_t)dir * BATCH * HDIM;
    const bf16* Wsrc = wt_h + (size_t)dir * 3 * HDIM * HDIM;

    // Stage weight slices into LDS in fragment order (once).
    for (int idx = threadIdx.x; idx < 3 * 32 * 64; idx += 256) {
        int gate = idx >> 11;          // / (32*64)
        int rem  = idx & 2047;
        int kc   = rem >> 6;
        int ln   = rem & 63;
        int n    = n0 + (ln & 15);
        int k    = kc * 32 + (ln >> 4) * 8;
        *(bf16x8*)&Wlds[(size_t)idx * 8] =
            *(const bf16x8*)(Wsrc + (size_t)gate * HDIM * HDIM + (size_t)n * HDIM + k);
    }
    __syncthreads();

    unsigned* bar_d = bar + dir * 1024;

    for (int step = 0; step < T_LEN; ++step) {
        int t = dir ? (T_LEN - 1 - step) : step;

        // ---------------- Phase A: R (gate 0) and Z (gate 1) ----------------
        {
            int gate = w >> 1, mt = w & 1;
            int m0 = gb * 32 + mt * 16;
            const bf16* A  = h_d + (size_t)(m0 + lm) * HDIM + lq * 8;
            const bf16* Bl = &Wlds[((size_t)(gate * 32) * 64 + l) * 8];
            f32x4 acc = {};
#pragma unroll 8
            for (int kc = 0; kc < 32; ++kc) {
                bf16x8 a = *(const bf16x8*)(A + kc * 32);
                bf16x8 b = *(const bf16x8*)(Bl + (size_t)kc * 64 * 8);
                acc = __builtin_amdgcn_mfma_f32_16x16x32_bf16(a, b, acc, 0, 0, 0);
            }
            const bf16* xp = XP + ((size_t)(dir * 3 + gate) * T_LEN + t) * BATCH * HDIM;
            int n = n0 + lm;
#pragma unroll
            for (int r = 0; r < 4; ++r) {
                int b_ = m0 + lq * 4 + r;
                float pre = acc[r] + (float)xp[(size_t)b_ * HDIM + n];
                float g = 1.0f / (1.0f + __expf(-pre));
                if (gate == 0) {
                    float hv = (float)h_d[(size_t)b_ * HDIM + n];
                    Rh_d[(size_t)b_ * HDIM + n] = (bf16)(g * hv);
                } else {
                    Zlds[mt][l][r] = g;
                }
            }
        }
        dir_barrier(&bar_d[step * 2], 128u);

        // ---------------- Phase B: h~ = tanh((R.h)@W_hh + xh); update h ------
        {
            int mt = w & 1, kh = w >> 1;
            int m0 = gb * 32 + mt * 16;
            const bf16* A  = Rh_d + (size_t)(m0 + lm) * HDIM + kh * 512 + lq * 8;
            const bf16* Bl = &Wlds[((size_t)(2 * 32 + kh * 16) * 64 + l) * 8];
            f32x4 acc = {};
#pragma unroll 8
            for (int kc = 0; kc < 16; ++kc) {
                bf16x8 a = *(const bf16x8*)(A + kc * 32);
                bf16x8 b = *(const bf16x8*)(Bl + (size_t)kc * 64 * 8);
                acc = __builtin_amdgcn_mfma_f32_16x16x32_bf16(a, b, acc, 0, 0, 0);
            }
            if (kh == 1) {
#pragma unroll
                for (int r = 0; r < 4; ++r) Red[mt][l][r] = acc[r];
            }
            __syncthreads();
            if (kh == 0) {
                const bf16* xp = XP + ((size_t)(dir * 3 + 2) * T_LEN + t) * BATCH * HDIM;
                int n = n0 + lm;
#pragma unroll
                for (int r = 0; r < 4; ++r) {
                    int b_ = m0 + lq * 4 + r;
                    float pre = acc[r] + Red[mt][l][r] + (float)xp[(size_t)b_ * HDIM + n];
                    float e2x = __expf(2.0f * pre);
                    float ht  = (e2x - 1.0f) / (e2x + 1.0f);
                    float z   = Zlds[mt][l][r];
                    float ho  = (float)h_d[(size_t)b_ * HDIM + n];
                    float hn  = z * ht + (1.0f - z) * ho;
                    h_d[(size_t)b_ * HDIM + n] = (bf16)hn;
                    out[((size_t)b_ * T_LEN + t) * (2 * HDIM) + (size_t)dir * HDIM + n] = hn;
                }
            }
        }
        dir_barrier(&bar_d[step * 2 + 1], 128u);
    }
}

// ---------------------------------------------------------------------------
extern "C" void kernel_launch(void* const* d_in, const int* in_sizes, int n_in,
                              void* d_out, int out_size, void* d_ws, size_t ws_size,
                              hipStream_t stream) {
    const float* x   = (const float*)d_in[0];
    const float* hpf = (const float*)d_in[1];
    const float* hpb = (const float*)d_in[2];

    // Workspace layout (bytes) — identical footprint to round 1.
    unsigned char* ws = (unsigned char*)d_ws;
    size_t off = 0;
    bf16* wt_h = (bf16*)(ws + off); off += (size_t)6 * HDIM * HDIM * 2;            // 12.58 MB
    bf16* wt_x = (bf16*)(ws + off); off += (size_t)6 * HDIM * IDIM * 2;            // 6.29 MB
    bf16* xbf  = (bf16*)(ws + off); off += (size_t)BATCH * T_LEN * IDIM * 2;       // 33.55 MB
    bf16* XP   = (bf16*)(ws + off); off += (size_t)6 * T_LEN * BATCH * HDIM * 2;   // 402.65 MB
    bf16* h_cur = (bf16*)(ws + off); off += (size_t)2 * BATCH * HDIM * 2;
    bf16* Rh    = (bf16*)(ws + off); off += (size_t)2 * BATCH * HDIM * 2;
    unsigned* bar = (unsigned*)(ws + off);   // 8 KB barrier counters (in old Zbuf region)

    float* out = (float*)d_out;

    // K0: weights transpose+convert
    Ptr12 wp;
    wp.p[0] = (const float*)d_in[3];  wp.p[1] = (const float*)d_in[6];  wp.p[2] = (const float*)d_in[9];
    wp.p[3] = (const float*)d_in[12]; wp.p[4] = (const float*)d_in[15]; wp.p[5] = (const float*)d_in[18];
    wp.p[6] = (const float*)d_in[4];  wp.p[7] = (const float*)d_in[7];  wp.p[8] = (const float*)d_in[10];
    wp.p[9] = (const float*)d_in[13]; wp.p[10] = (const float*)d_in[16]; wp.p[11] = (const float*)d_in[19];
    transpose_convert<<<dim3(32, 32, 12), 256, 0, stream>>>(wp, wt_h, wt_x);

    // K0b: x -> bf16
    convert_x<<<16384, 256, 0, stream>>>(x, xbf);

    // K0c: init h
    init_h<<<256, 256, 0, stream>>>(hpf, hpb, h_cur);

    // Barrier counters must start at 0 (ws is poisoned before every launch).
    hipMemsetAsync(bar, 0, 2 * 1024 * sizeof(unsigned), stream);

    // K1: xproj
    Ptr6 bp;
    bp.p[0] = (const float*)d_in[5];  bp.p[1] = (const float*)d_in[8];  bp.p[2] = (const float*)d_in[11];
    bp.p[3] = (const float*)d_in[14]; bp.p[4] = (const float*)d_in[17]; bp.p[5] = (const float*)d_in[20];
    xproj_gemm<<<dim3(512, 16, 6), 256, 0, stream>>>(xbf, wt_x, bp, XP);

    // K2: persistent recurrence (512 steps, 2 device barriers/step, in one launch)
    gru_persist<<<256, 256, 0, stream>>>(wt_h, XP, h_cur, Rh, out, bar);
}